// Round 4
// baseline (317.075 us; speedup 1.0000x reference)
//
#include <hip/hip_runtime.h>
#include <hip/hip_cooperative_groups.h>
#include <math.h>

namespace cg = cooperative_groups;

#define BLOCK 256
#define SLICE 8192                     // samples per slice (per block per iteration)
#define PASSES (SLICE / (BLOCK * 4))   // 8 coalesced float4 passes per slice
#define KSLOT 32                       // max stored transitions per slice
#define SORT_CAP 4096                  // max total transitions
#define SEG_CAP 2048                   // LDS segment cache for phase C
#define MAXGRID 1024                   // co-residency-safe block count (4/CU)

struct SegRec { float p0; int type; };  // 0=pre-note silence, 1=gated note, 2=release

__device__ __forceinline__ int wave_scan_i(int v) {
#pragma unroll
    for (int d = 1; d < 64; d <<= 1) {
        int n = __shfl_up(v, d, 64);
        if ((threadIdx.x & 63) >= d) v += n;
    }
    return v;
}
__device__ __forceinline__ float wave_scan_f(float v) {
#pragma unroll
    for (int d = 1; d < 64; d <<= 1) {
        float n = __shfl_up(v, d, 64);
        if ((threadIdx.x & 63) >= d) v += n;
    }
    return v;
}
// 256-thread block scans (inclusive); also return block total. End with sync so
// the scratch can be reused by the next call.
__device__ __forceinline__ int block_scan_i(int v, int* lds4, int* total) {
    const int lane = threadIdx.x & 63, w = threadIdx.x >> 6;
    int s = wave_scan_i(v);
    if (lane == 63) lds4[w] = s;
    __syncthreads();
    int add = 0, tot = 0;
#pragma unroll
    for (int q = 0; q < BLOCK / 64; ++q) { if (q < w) add += lds4[q]; tot += lds4[q]; }
    *total = tot;
    __syncthreads();
    return s + add;
}
__device__ __forceinline__ float block_scan_f(float v, float* lds4, float* total) {
    const int lane = threadIdx.x & 63, w = threadIdx.x >> 6;
    float s = wave_scan_f(v);
    if (lane == 63) lds4[w] = s;
    __syncthreads();
    float add = 0.0f, tot = 0.0f;
#pragma unroll
    for (int q = 0; q < BLOCK / 64; ++q) { if (q < w) add += lds4[q]; tot += lds4[q]; }
    *total = tot;
    __syncthreads();
    return s + add;
}

__global__ __launch_bounds__(BLOCK, 4) void k_fused(
    const float* __restrict__ g, int T, int nslice,
    int* __restrict__ counts, int* __restrict__ chunk_tr,
    int* __restrict__ seg_starts, SegRec* __restrict__ recs, int* __restrict__ nseg_p,
    const float* __restrict__ attack_p, const float* __restrict__ decay_p,
    const float* __restrict__ sustain_p, const float* __restrict__ release_p,
    float* __restrict__ out)
{
    // LDS: phase B uses it as s_tr[SORT_CAP] (16 KB); phase C as 3 seg arrays (24 KB)
    __shared__ __align__(16) char shraw[SEG_CAP * 12];
    int*   s_tr     = (int*)shraw;
    int*   c_start  = (int*)shraw;
    float* c_p0     = (float*)(shraw + SEG_CAP * 4);
    int*   c_type   = (int*)(shraw + SEG_CAP * 8);
    __shared__ int   ldsi[BLOCK / 64];
    __shared__ float ldsf[BLOCK / 64];

    const int tid = threadIdx.x;

    // ---------------- Phase A: transition detection per slice ----------------
    for (int sl = blockIdx.x; sl < nslice; sl += gridDim.x) {
        const long s0 = (long)sl * SLICE;
        int B = 0;
        for (int q = 0; q < PASSES; ++q) {
            const long i0 = s0 + (long)q * (BLOCK * 4) + (long)tid * 4;
            int m = 0;
            if (i0 + 3 < (long)T) {
                const float4 v = *reinterpret_cast<const float4*>(g + i0);
                float prev = __shfl_up(v.w, 1, 64);
                if ((tid & 63) == 0) prev = (i0 > 0) ? g[i0 - 1] : v.x;
                m = (int)(v.x != prev) | ((int)(v.y != v.x) << 1) |
                    ((int)(v.z != v.y) << 2) | ((int)(v.w != v.z) << 3);
            } else if (i0 < (long)T) {
                float prev = (i0 > 0) ? g[i0 - 1] : g[i0];
                for (int e = 0; e < 4 && i0 + e < (long)T; ++e) {
                    const float cur = g[i0 + e];
                    if ((i0 + e) > 0 && cur != prev) m |= (1 << e);
                    prev = cur;
                }
            }
            const int c = __popc(m);
            int tot;
            const int incl = block_scan_i(c, ldsi, &tot);
            if (m) {
                int pos = B + incl - c;
#pragma unroll
                for (int e = 0; e < 4; ++e) {
                    if (m & (1 << e)) {
                        if (pos < KSLOT) chunk_tr[(long)sl * KSLOT + pos] = (int)(i0 + e);
                        ++pos;
                    }
                }
            }
            B += tot;
        }
        if (tid == 0) counts[sl] = (B < KSLOT) ? B : KSLOT;
    }
    __threadfence();
    cg::this_grid().sync();

    const float attack = *attack_p, decay = *decay_p;
    const float sustain = *sustain_p, release = *release_p;
    const float dlog2 = log2f(expf(-1.0f / decay));
    const float rlog2 = log2f(expf(-1.0f / release));

    // ---------------- Phase B: block 0 builds segment records ----------------
    if (blockIdx.x == 0) {
        int carry = 0;
        for (int cb = 0; cb < nslice; cb += BLOCK) {
            const int cidx = cb + tid;
            int cnt = (cidx < nslice) ? counts[cidx] : 0;
            cnt = (cnt < 0) ? 0 : ((cnt > KSLOT) ? KSLOT : cnt);
            int tot;
            const int incl = block_scan_i(cnt, ldsi, &tot);
            const int off = carry + incl - cnt;
            for (int e = 0; e < cnt; ++e) {
                const int idx = off + e;
                if (idx < SORT_CAP) s_tr[idx] = chunk_tr[(long)cidx * KSLOT + e];
            }
            carry += tot;
        }
        __syncthreads();
        const int ntrans = (carry < SORT_CAP) ? carry : SORT_CAP;
        const bool g0 = (g[0] != 0.0f);
        const int nseg = ntrans + 1;
        if (tid == 0) *nseg_p = nseg;

        float fcarry = 0.0f;
        for (int basej = 0; basej < nseg; basej += BLOCK) {
            const int j = basej + tid;
            const bool valid = (j < nseg);
            int start = 0; bool gated = false; float r = 0.0f;
            if (valid) {
                start = (j == 0) ? 0 : s_tr[j - 1];
                gated = ((j & 1) == 0) ? g0 : !g0;
                if (gated && j >= 2) {
                    const int t1 = s_tr[j - 2];
                    const int t2 = (j == 2) ? 0 : s_tr[j - 3];
                    const float lenprev = (float)(t1 - t2);   // prev note length at note-off
                    const float seedp = (lenprev > attack)
                        ? (sustain + (1.0f - sustain) * exp2f((lenprev - attack) * dlog2))
                        : 1.0f;                                // note-off during attack
                    const float gap = (float)(start - t1);     // release run length
                    if (1.0f <= attack) r = seedp * exp2f(gap * rlog2);
                }
            }
            float ftot;
            const float fincl = block_scan_f(r, ldsf, &ftot);
            if (valid) {
                seg_starts[j] = start;
                SegRec rec;
                if (gated)      { rec.type = 1; rec.p0 = fcarry + fincl; }  // inclusive A-prefix
                else if (j == 0){ rec.type = 0; rec.p0 = 0.0f; }
                else {
                    const int sp = (j == 1) ? 0 : s_tr[j - 2];
                    const float len = (float)(start - sp);
                    rec.type = 2;
                    rec.p0 = (len > attack)
                        ? (sustain + (1.0f - sustain) * exp2f((len - attack) * dlog2))
                        : 1.0f;
                }
                recs[j] = rec;
            }
            fcarry += ftot;
        }
        __threadfence();
    }
    cg::this_grid().sync();

    // ---------------- Phase C: per-sample evaluation ----------------
    const int nseg = *nseg_p;
    const bool useLds = (nseg <= SEG_CAP);
    if (useLds) {
        for (int j = tid; j < nseg; j += BLOCK) {
            c_start[j] = seg_starts[j];
            const SegRec rr = recs[j];
            c_p0[j] = rr.p0;
            c_type[j] = rr.type;
        }
    }
    __syncthreads();
    const float inv_attack = 1.0f / attack;

    for (int sl = blockIdx.x; sl < nslice; sl += gridDim.x) {
        const long s0 = (long)sl * SLICE;
        // binary search for the thread's first sample; then advance monotonically
        int j;
        {
            const long ifirst = s0 + (long)tid * 4;
            int lo = 0, hi = nseg - 1;
            if (useLds) { while (lo < hi) { const int mid = (lo + hi + 1) >> 1; if ((long)c_start[mid] <= ifirst) lo = mid; else hi = mid - 1; } }
            else        { while (lo < hi) { const int mid = (lo + hi + 1) >> 1; if ((long)seg_starts[mid] <= ifirst) lo = mid; else hi = mid - 1; } }
            j = lo;
        }
        for (int q = 0; q < PASSES; ++q) {
            const long i0 = s0 + (long)q * (BLOCK * 4) + (long)tid * 4;
            if (i0 >= (long)T) break;
            float res[4];
#pragma unroll
            for (int e = 0; e < 4; ++e) {
                const long i = i0 + e;
                if (i < (long)T) {
                    if (useLds) { while (j + 1 < nseg && (long)c_start[j + 1] <= i) ++j; }
                    else        { while (j + 1 < nseg && (long)seg_starts[j + 1] <= i) ++j; }
                    const int   type = useLds ? c_type[j] : recs[j].type;
                    const float p0   = useLds ? c_p0[j]   : recs[j].p0;
                    const int   st   = useLds ? c_start[j] : seg_starts[j];
                    float v;
                    if (type == 1) {
                        const float ad = (float)(i - st + 1);  // samples since note-on
                        v = (ad <= attack) ? ((1.0f - p0) * ad * inv_attack + p0)
                                           : (sustain + (1.0f - sustain) * exp2f((ad - attack) * dlog2));
                    } else if (type == 2) {
                        const float k = (float)(i - st + 1);   // samples since note-off
                        v = p0 * exp2f(k * rlog2);
                    } else {
                        v = 0.0f;
                    }
                    res[e] = v;
                } else {
                    res[e] = 0.0f;
                }
            }
            if (i0 + 3 < (long)T) {
                *reinterpret_cast<float4*>(out + i0) = make_float4(res[0], res[1], res[2], res[3]);
            } else {
                for (int e = 0; e < 4 && i0 + e < (long)T; ++e) out[i0 + e] = res[e];
            }
        }
    }
}

extern "C" void kernel_launch(void* const* d_in, const int* in_sizes, int n_in,
                              void* d_out, int out_size, void* d_ws, size_t ws_size,
                              hipStream_t stream) {
    const float* gate    = (const float*)d_in[0];
    const float* attack  = (const float*)d_in[1];
    const float* decay   = (const float*)d_in[2];
    const float* sustain = (const float*)d_in[3];
    const float* release = (const float*)d_in[4];
    float* out = (float*)d_out;
    int T = in_sizes[0];
    int nslice = (T + SLICE - 1) / SLICE;

    // workspace layout (8B-aligned)
    char* w = (char*)d_ws;
    int* nseg_p     = (int*)(w + 8);
    int* counts     = (int*)(w + 256);                    // nslice ints
    int* chunk_tr   = counts + nslice;                    // nslice*KSLOT ints
    int* seg_starts = chunk_tr + (long)nslice * KSLOT;    // SORT_CAP+2 ints
    SegRec* recs    = (SegRec*)(seg_starts + SORT_CAP + 2);

    int grid = (nslice < MAXGRID) ? nslice : MAXGRID;

    void* args[] = {
        (void*)&gate, (void*)&T, (void*)&nslice,
        (void*)&counts, (void*)&chunk_tr,
        (void*)&seg_starts, (void*)&recs, (void*)&nseg_p,
        (void*)&attack, (void*)&decay, (void*)&sustain, (void*)&release,
        (void*)&out
    };
    hipLaunchCooperativeKernel((const void*)k_fused, dim3(grid), dim3(BLOCK),
                               args, 0, stream);
}

// Round 5
// 48.725 us; speedup vs baseline: 6.5074x; 6.5074x over previous
//
#include <hip/hip_runtime.h>
#include <math.h>

#define CHUNK 4096
#define K1_BLOCK 256
#define EPT 16          // 256*16 = 4096 elements per collect block
#define KSLOT 16        // max stored transitions per chunk
#define SEGCAP 2048     // max segments (LDS tables in k_eval, 24 KB)

__device__ __forceinline__ int wave_scan_i(int v) {
#pragma unroll
    for (int d = 1; d < 64; d <<= 1) {
        int n = __shfl_up(v, d, 64);
        if ((threadIdx.x & 63) >= d) v += n;
    }
    return v;
}
__device__ __forceinline__ float wave_scan_f(float v) {
#pragma unroll
    for (int d = 1; d < 64; d <<= 1) {
        float n = __shfl_up(v, d, 64);
        if ((threadIdx.x & 63) >= d) v += n;
    }
    return v;
}
// 256-thread block inclusive scan + total; safe for back-to-back reuse.
__device__ __forceinline__ int block_scan_i(int v, int* lds4, int* total) {
    const int lane = threadIdx.x & 63, w = threadIdx.x >> 6;
    int s = wave_scan_i(v);
    if (lane == 63) lds4[w] = s;
    __syncthreads();
    int add = 0, tot = 0;
#pragma unroll
    for (int q = 0; q < 4; ++q) { if (q < w) add += lds4[q]; tot += lds4[q]; }
    *total = tot;
    __syncthreads();
    return s + add;
}
__device__ __forceinline__ float block_scan_f(float v, float* lds4, float* total) {
    const int lane = threadIdx.x & 63, w = threadIdx.x >> 6;
    float s = wave_scan_f(v);
    if (lane == 63) lds4[w] = s;
    __syncthreads();
    float add = 0.0f, tot = 0.0f;
#pragma unroll
    for (int q = 0; q < 4; ++q) { if (q < w) add += lds4[q]; tot += lds4[q]; }
    *total = tot;
    __syncthreads();
    return s + add;
}

// ---- Node 1: per-chunk transition detection -> fixed ordered slots ----
__global__ void k_collect(const float* __restrict__ g, int T,
                          int* __restrict__ counts, int* __restrict__ chunk_tr) {
    const int tid = threadIdx.x;
    const long base = (long)blockIdx.x * CHUNK + (long)tid * EPT;
    float vals[EPT];
    float prevFirst = 0.0f;
    int n = 0;
    if (base < T) {
        const long rem = (long)T - base;
        n = (int)(rem < EPT ? rem : (long)EPT);
        prevFirst = (base > 0) ? g[base - 1] : 0.0f;  // i==0 guarded below
        if (n == EPT) {
#pragma unroll
            for (int q = 0; q < EPT / 4; ++q) {
                const float4 v = *reinterpret_cast<const float4*>(g + base + q * 4);
                vals[q * 4 + 0] = v.x; vals[q * 4 + 1] = v.y;
                vals[q * 4 + 2] = v.z; vals[q * 4 + 3] = v.w;
            }
        } else {
            for (int e = 0; e < n; ++e) vals[e] = g[base + e];
        }
    }
    int c = 0;
    {
        float prev = prevFirst;
        for (int e = 0; e < n; ++e) {
            const long i = base + e;
            if (i > 0 && vals[e] != prev) ++c;
            prev = vals[e];
        }
    }
    __shared__ int lds4[4];
    int tot;
    const int incl = block_scan_i(c, lds4, &tot);
    if (tid == 0) counts[blockIdx.x] = (tot < KSLOT) ? tot : KSLOT;
    if (c) {
        int pos = incl - c;
        float prev = prevFirst;
        for (int e = 0; e < n; ++e) {
            const long i = base + e;
            if (i > 0 && vals[e] != prev) {
                if (pos < KSLOT) chunk_tr[(long)blockIdx.x * KSLOT + pos] = (int)i;
                ++pos;
            }
            prev = vals[e];
        }
    }
}

// ---- Node 2: every block rebuilds the segment table in LDS, then evaluates its chunk ----
__global__ void __launch_bounds__(K1_BLOCK) k_eval(
    const float* __restrict__ g, int T, int nchunk,
    const int* __restrict__ counts, const int* __restrict__ chunk_tr,
    const float* __restrict__ attack_p, const float* __restrict__ decay_p,
    const float* __restrict__ sustain_p, const float* __restrict__ release_p,
    float* __restrict__ out)
{
    __shared__ int   c_start[SEGCAP];   // c_start[0]=0; c_start[m+1]=transition m
    __shared__ float c_p0[SEGCAP];
    __shared__ int   c_type[SEGCAP];
    __shared__ int   ldsi[4];
    __shared__ float ldsf[4];

    const int tid = threadIdx.x;

    // ---- compaction: thread t owns chunks [t*PER, (t+1)*PER) ----
    const int PER = (nchunk + K1_BLOCK - 1) / K1_BLOCK;
    const int c0 = tid * PER;
    int mycnt[32];                       // PER <= 32 for T up to 2^25
    int mysum = 0;
    for (int k = 0; k < PER; ++k) {
        const int cidx = c0 + k;
        int c = (cidx < nchunk) ? counts[cidx] : 0;
        c = (c < 0) ? 0 : ((c > KSLOT) ? KSLOT : c);
        mycnt[k] = c;
        mysum += c;
    }
    int tot;
    const int incl = block_scan_i(mysum, ldsi, &tot);
    int off = incl - mysum;              // transitions before my chunks
    for (int k = 0; k < PER; ++k) {
        const int c = mycnt[k];
        for (int e = 0; e < c; ++e) {
            const int dst = off + e + 1; // +1: c_start[0] is the origin
            if (dst < SEGCAP) c_start[dst] = chunk_tr[(long)(c0 + k) * KSLOT + e];
        }
        off += c;
    }
    if (tid == 0) c_start[0] = 0;
    const int ntrans = (tot < SEGCAP - 1) ? tot : (SEGCAP - 1);
    const int nseg = ntrans + 1;
    __syncthreads();

    const float attack = *attack_p, decay = *decay_p;
    const float sustain = *sustain_p, release = *release_p;
    const float dlog2 = log2f(expf(-1.0f / decay));
    const float rlog2 = log2f(expf(-1.0f / release));
    const bool g0 = (g[0] != 0.0f);

    // ---- segment records (type, p0) + retrigger-seed prefix scan ----
    float fcarry = 0.0f;
    for (int basej = 0; basej < nseg; basej += K1_BLOCK) {
        const int j = basej + tid;
        const bool valid = (j < nseg);
        bool gated = false;
        float r = 0.0f;
        int start = 0;
        if (valid) {
            start = c_start[j];
            gated = ((j & 1) == 0) ? g0 : !g0;
            if (gated && j >= 2) {
                const int t1 = c_start[j - 1];            // prev note start? no: prev seg start
                const int t2 = c_start[j - 2];            // prev note start
                const float lenprev = (float)(t1 - t2);   // prev note length at note-off
                const float seedp = (lenprev > attack)
                    ? (sustain + (1.0f - sustain) * exp2f((lenprev - attack) * dlog2))
                    : 1.0f;                               // note-off during attack
                const float gap = (float)(start - t1);    // release run length
                if (1.0f <= attack) r = seedp * exp2f(gap * rlog2);
            }
        }
        float ftot;
        const float fincl = block_scan_f(r, ldsf, &ftot);
        if (valid) {
            if (gated) { c_type[j] = 1; c_p0[j] = fcarry + fincl; }   // inclusive A-prefix
            else if (j == 0) { c_type[j] = 0; c_p0[j] = 0.0f; }
            else {
                const int sp = c_start[j - 1];            // prev note start
                const float len = (float)(start - sp);
                c_type[j] = 2;
                c_p0[j] = (len > attack)
                    ? (sustain + (1.0f - sustain) * exp2f((len - attack) * dlog2))
                    : 1.0f;
            }
        }
        fcarry += ftot;
    }
    __syncthreads();

    // ---- evaluate this block's 4096-sample chunk ----
    const float inv_attack = 1.0f / attack;
    const long base = (long)blockIdx.x * CHUNK;
    int j;
    {
        const long ifirst = base + (long)tid * 4;
        int lo = 0, hi = nseg - 1;
        while (lo < hi) {
            const int mid = (lo + hi + 1) >> 1;
            if ((long)c_start[mid] <= ifirst) lo = mid; else hi = mid - 1;
        }
        j = lo;
    }
#pragma unroll
    for (int q = 0; q < CHUNK / (K1_BLOCK * 4); ++q) {
        const long i0 = base + (long)q * (K1_BLOCK * 4) + (long)tid * 4;
        if (i0 >= (long)T) break;
        float res[4];
#pragma unroll
        for (int e = 0; e < 4; ++e) {
            const long i = i0 + e;
            if (i < (long)T) {
                while (j + 1 < nseg && (long)c_start[j + 1] <= i) ++j;
                const int   type = c_type[j];
                const float p0   = c_p0[j];
                const int   st   = c_start[j];
                float v;
                if (type == 1) {
                    const float ad = (float)(i - st + 1);   // samples since note-on
                    v = (ad <= attack) ? ((1.0f - p0) * ad * inv_attack + p0)
                                       : (sustain + (1.0f - sustain) * exp2f((ad - attack) * dlog2));
                } else if (type == 2) {
                    const float k = (float)(i - st + 1);    // samples since note-off
                    v = p0 * exp2f(k * rlog2);
                } else {
                    v = 0.0f;
                }
                res[e] = v;
            } else {
                res[e] = 0.0f;
            }
        }
        if (i0 + 3 < (long)T) {
            *reinterpret_cast<float4*>(out + i0) = make_float4(res[0], res[1], res[2], res[3]);
        } else {
            for (int e = 0; e < 4 && i0 + e < (long)T; ++e) out[i0 + e] = res[e];
        }
    }
}

extern "C" void kernel_launch(void* const* d_in, const int* in_sizes, int n_in,
                              void* d_out, int out_size, void* d_ws, size_t ws_size,
                              hipStream_t stream) {
    const float* gate    = (const float*)d_in[0];
    const float* attack  = (const float*)d_in[1];
    const float* decay   = (const float*)d_in[2];
    const float* sustain = (const float*)d_in[3];
    const float* release = (const float*)d_in[4];
    float* out = (float*)d_out;
    const int T = in_sizes[0];
    const int nchunk = (T + CHUNK - 1) / CHUNK;

    // workspace: counts (nchunk ints) + chunk_tr (nchunk*KSLOT ints)
    char* w = (char*)d_ws;
    int* counts   = (int*)(w + 256);
    int* chunk_tr = counts + nchunk;

    k_collect<<<nchunk, K1_BLOCK, 0, stream>>>(gate, T, counts, chunk_tr);
    k_eval<<<nchunk, K1_BLOCK, 0, stream>>>(gate, T, nchunk, counts, chunk_tr,
                                            attack, decay, sustain, release, out);
}